// Round 1
// baseline (282.194 us; speedup 1.0000x reference)
//
#include <hip/hip_runtime.h>

// DilatedReparamBlock (13x13, non-deploy) reparameterized into a single
// 13x13 depthwise conv + bias, computed per-plane in LDS.
//
// x: [16,384,56,56] f32. out same. 7 branches folded:
//   W_eq[c] = sum_j s_j * dilate(w_j),  bias[c] = sum_j t_j
//   s_j = gamma/sqrt(var+eps), t_j = beta - mean*s_j

#define CCH 384
#define SP 56
#define PAD 6
#define PW 68           // 56 + 2*6
#define NPLANES (16*384)
#define BLK 448         // 7 waves: (xg 0..7) x (y 0..55), 7 outputs per thread

__global__ __launch_bounds__(BLK) void drb_conv13(
    const float* __restrict__ x,
    const float* __restrict__ w_lk, const float* __restrict__ w_b0,
    const float* __restrict__ w_b1, const float* __restrict__ w_b2,
    const float* __restrict__ w_b3, const float* __restrict__ w_b4,
    const float* __restrict__ w_b5,
    const float* __restrict__ gamma, const float* __restrict__ beta,
    const float* __restrict__ mean, const float* __restrict__ var,
    float* __restrict__ out)
{
    __shared__ float sx[PW * PW];     // padded input plane, 18496 B
    __shared__ float sw[13 * 16];     // merged 13x13 weights, row-padded to 16
    __shared__ float sS[7], sT[7];
    __shared__ float sbias;

    const int plane = blockIdx.x;          // n*384 + c
    const int c = plane % CCH;
    const float* __restrict__ xp = x + (size_t)plane * (SP * SP);
    float* __restrict__ op = out + (size_t)plane * (SP * SP);
    const int tid = threadIdx.x;

    // --- BN scale/shift per branch (block-redundant, tiny) ---
    if (tid < 7) {
        float inv = gamma[tid * CCH + c] * rsqrtf(var[tid * CCH + c] + 1e-5f);
        sS[tid] = inv;
        sT[tid] = beta[tid * CCH + c] - mean[tid * CCH + c] * inv;
    }
    // --- zero the padded tile (halo) ---
    for (int i = tid; i < PW * PW; i += BLK) sx[i] = 0.f;
    __syncthreads();

    // --- build merged 13x13 weights in LDS ---
    if (tid < 13 * 16) {
        int ky = tid >> 4, kx = tid & 15;
        float w = 0.f;
        if (kx < 13) {
            w = sS[0] * w_lk[c * 169 + ky * 13 + kx];                     // 13x13 d1
            if (ky >= 4 && ky <= 8 && kx >= 4 && kx <= 8)                 // 5x5 d1 @4
                w += sS[1] * w_b0[c * 25 + (ky - 4) * 5 + (kx - 4)];
            if (ky >= 3 && ky <= 9 && kx >= 3 && kx <= 9)                 // 7x7 d1 @3
                w += sS[2] * w_b1[c * 49 + (ky - 3) * 7 + (kx - 3)];
            if (!(ky & 1) && !(kx & 1))                                   // 7x7 d2 @0,2,..
                w += sS[3] * w_b2[c * 49 + (ky >> 1) * 7 + (kx >> 1)];
            if (ky >= 3 && ky <= 9 && (ky - 3) % 3 == 0 &&
                kx >= 3 && kx <= 9 && (kx - 3) % 3 == 0)                  // 3x3 d3 @3,6,9
                w += sS[4] * w_b3[c * 9 + ((ky - 3) / 3) * 3 + (kx - 3) / 3];
            if (ky >= 2 && ky <= 10 && (ky - 2) % 4 == 0 &&
                kx >= 2 && kx <= 10 && (kx - 2) % 4 == 0)                 // 3x3 d4 @2,6,10
                w += sS[5] * w_b4[c * 9 + ((ky - 2) / 4) * 3 + (kx - 2) / 4];
            if (ky >= 1 && ky <= 11 && (ky - 1) % 5 == 0 &&
                kx >= 1 && kx <= 11 && (kx - 1) % 5 == 0)                 // 3x3 d5 @1,6,11
                w += sS[6] * w_b5[c * 9 + ((ky - 1) / 5) * 3 + (kx - 1) / 5];
        }
        sw[tid] = w;
    }
    if (tid == BLK - 1)
        sbias = sT[0] + sT[1] + sT[2] + sT[3] + sT[4] + sT[5] + sT[6];

    // --- stage the 56x56 interior (coalesced; 7 iters/thread exactly) ---
    for (int i = tid; i < SP * SP; i += BLK) {
        int r = i / SP;
        int col = i - r * SP;
        sx[(r + PAD) * PW + col + PAD] = xp[i];
    }
    __syncthreads();

    // --- compute: thread (xg, y) -> outputs [y][7*xg .. 7*xg+6] ---
    const int xg = tid & 7;    // 0..7 -> x0 = 0,7,...,49
    const int y  = tid >> 3;   // 0..55
    const float* __restrict__ srow = &sx[y * PW + xg * 7];

    float acc[7] = {0.f, 0.f, 0.f, 0.f, 0.f, 0.f, 0.f};
    #pragma unroll 1
    for (int ky = 0; ky < 13; ky++) {
        float in[19];
        #pragma unroll
        for (int i = 0; i < 19; i++) in[i] = srow[ky * PW + i];
        const float* __restrict__ wr = &sw[ky * 16];
        #pragma unroll
        for (int kx = 0; kx < 13; kx++) {
            const float w = wr[kx];
            #pragma unroll
            for (int j = 0; j < 7; j++)
                acc[j] = fmaf(w, in[kx + j], acc[j]);
        }
    }

    const float b = sbias;
    float* __restrict__ orow = op + y * SP + xg * 7;
    #pragma unroll
    for (int j = 0; j < 7; j++) orow[j] = acc[j] + b;
}

extern "C" void kernel_launch(void* const* d_in, const int* in_sizes, int n_in,
                              void* d_out, int out_size, void* d_ws, size_t ws_size,
                              hipStream_t stream) {
    const float* x    = (const float*)d_in[0];
    const float* w_lk = (const float*)d_in[1];
    const float* w_b0 = (const float*)d_in[2];
    const float* w_b1 = (const float*)d_in[3];
    const float* w_b2 = (const float*)d_in[4];
    const float* w_b3 = (const float*)d_in[5];
    const float* w_b4 = (const float*)d_in[6];
    const float* w_b5 = (const float*)d_in[7];
    const float* bn_g = (const float*)d_in[8];
    const float* bn_b = (const float*)d_in[9];
    const float* bn_m = (const float*)d_in[10];
    const float* bn_v = (const float*)d_in[11];
    float* out = (float*)d_out;

    drb_conv13<<<dim3(NPLANES), dim3(BLK), 0, stream>>>(
        x, w_lk, w_b0, w_b1, w_b2, w_b3, w_b4, w_b5,
        bn_g, bn_b, bn_m, bn_v, out);
}

// Round 2
// 245.876 us; speedup vs baseline: 1.1477x; 1.1477x over previous
//
#include <hip/hip_runtime.h>

// DilatedReparamBlock folded into one 13x13 depthwise conv + bias.
// Wave-per-plane: block = 64 threads = 1 wave = 1 plane (56x56).
// Thread (xg,yg): 7-row x 8-col output patch (xg<7 active; 8 yg groups).
// Input plane staged padded (68x68) in LDS; windows read as ds_read_b128
// (16B-aligned since col base = 8*xg and row stride 68*4B = 272B % 16 == 0).
// K-loop: ky in pairs -> each LDS input row read once serves 2 (r,ky) pairs,
// cutting LDS traffic ~4x vs row-per-thread; weights held in VGPRs per pair.

#define CCH 384
#define SP 56
#define PW 68              // 56 + 2*6 padding
#define NPLANES (16*384)

__global__ __launch_bounds__(64) void drb_conv13_w64(
    const float* __restrict__ x,
    const float* __restrict__ w_lk, const float* __restrict__ w_b0,
    const float* __restrict__ w_b1, const float* __restrict__ w_b2,
    const float* __restrict__ w_b3, const float* __restrict__ w_b4,
    const float* __restrict__ w_b5,
    const float* __restrict__ gamma, const float* __restrict__ beta,
    const float* __restrict__ mean, const float* __restrict__ var,
    float* __restrict__ out)
{
    __shared__ __align__(16) float sx[PW * PW];   // 18496 B padded plane
    __shared__ __align__(16) float sw[13 * 16];   // merged weights, rows padded to 16

    const int plane = blockIdx.x;                 // n*384 + c
    const int c = plane % CCH;
    const int tid = threadIdx.x;
    const float* __restrict__ xp = x + (size_t)plane * (SP * SP);

    // --- BN fold constants (wave-uniform -> scalar loads) ---
    float S[7];
    float bias = 0.f;
    #pragma unroll
    for (int j = 0; j < 7; j++) {
        float inv = gamma[j * CCH + c] * rsqrtf(var[j * CCH + c] + 1e-5f);
        S[j] = inv;
        bias += beta[j * CCH + c] - mean[j * CCH + c] * inv;
    }

    // --- zero padded tile (b128 stores) ---
    {
        float4 z = make_float4(0.f, 0.f, 0.f, 0.f);
        #pragma unroll
        for (int k = 0; k < 19; k++) {
            int i = tid + 64 * k;
            if (i < PW * PW / 4) ((float4*)sx)[i] = z;
        }
    }

    // --- build merged 13x13 weights (208 slots incl. row pad) ---
    #pragma unroll
    for (int k = 0; k < 4; k++) {
        int t = tid + 64 * k;
        if (t < 13 * 16) {
            int ky = t >> 4, kx = t & 15;
            float w = 0.f;
            if (kx < 13) {
                w = S[0] * w_lk[c * 169 + ky * 13 + kx];                   // 13x13 d1
                if (ky >= 4 && ky <= 8 && kx >= 4 && kx <= 8)              // 5x5 d1 @4
                    w += S[1] * w_b0[c * 25 + (ky - 4) * 5 + (kx - 4)];
                if (ky >= 3 && ky <= 9 && kx >= 3 && kx <= 9)              // 7x7 d1 @3
                    w += S[2] * w_b1[c * 49 + (ky - 3) * 7 + (kx - 3)];
                if (!(ky & 1) && !(kx & 1))                                // 7x7 d2
                    w += S[3] * w_b2[c * 49 + (ky >> 1) * 7 + (kx >> 1)];
                if (ky >= 3 && ky <= 9 && (ky - 3) % 3 == 0 &&
                    kx >= 3 && kx <= 9 && (kx - 3) % 3 == 0)               // 3x3 d3
                    w += S[4] * w_b3[c * 9 + ((ky - 3) / 3) * 3 + (kx - 3) / 3];
                if (ky >= 2 && ky <= 10 && (ky - 2) % 4 == 0 &&
                    kx >= 2 && kx <= 10 && (kx - 2) % 4 == 0)              // 3x3 d4
                    w += S[5] * w_b4[c * 9 + ((ky - 2) / 4) * 3 + (kx - 2) / 4];
                if (ky >= 1 && ky <= 11 && (ky - 1) % 5 == 0 &&
                    kx >= 1 && kx <= 11 && (kx - 1) % 5 == 0)              // 3x3 d5
                    w += S[6] * w_b5[c * 9 + ((ky - 1) / 5) * 3 + (kx - 1) / 5];
            }
            sw[t] = w;
        }
    }

    // --- stage plane: 784 float4 global loads -> 2x b64 LDS writes each ---
    #pragma unroll
    for (int k = 0; k < 13; k++) {
        int i4 = tid + 64 * k;
        if (i4 < SP * SP / 4) {
            float4 v = ((const float4*)xp)[i4];
            int r = i4 / 14;                 // 14 float4 per 56-wide row
            int col = (i4 - r * 14) * 4;
            float* d = &sx[(r + 6) * PW + col + 6];   // word-even -> 8B aligned
            ((float2*)d)[0] = make_float2(v.x, v.y);
            ((float2*)d)[1] = make_float2(v.z, v.w);
        }
    }
    __syncthreads();

    // --- compute: lane (xg,yg) -> out rows [7yg..7yg+6], cols [8xg..8xg+7] ---
    const int xg = tid & 7;
    const int yg = tid >> 3;
    const int xgc = (xg < 7) ? xg : 6;       // clamp idle lanes' addresses
    const int Yb = yg * 7;
    const float* __restrict__ sbase = &sx[Yb * PW + 8 * xgc];

    float acc[7][8];
    #pragma unroll
    for (int r = 0; r < 7; r++)
        #pragma unroll
        for (int j = 0; j < 8; j++) acc[r][j] = 0.f;

    // ky pairs (0,1)(2,3)...(10,11): 8 input rows per pair, each serving
    // (r=i, ky=k0) and (r=i-1, ky=k0+1).
    #pragma unroll 1
    for (int k0 = 0; k0 < 12; k0 += 2) {
        float4 w0[4], w1[4];
        #pragma unroll
        for (int q = 0; q < 4; q++) {
            w0[q] = ((const float4*)&sw[k0 * 16])[q];
            w1[q] = ((const float4*)&sw[(k0 + 1) * 16])[q];
        }
        const float* sr = sbase + k0 * PW;
        #pragma unroll
        for (int i = 0; i < 8; i++) {
            float4 win4[5];
            #pragma unroll
            for (int q = 0; q < 5; q++)
                win4[q] = *(const float4*)(sr + i * PW + 4 * q);
            const float* win = (const float*)win4;
            if (i < 7) {
                #pragma unroll
                for (int kx = 0; kx < 13; kx++) {
                    const float wv = ((const float*)w0)[kx];
                    #pragma unroll
                    for (int j = 0; j < 8; j++)
                        acc[i][j] = fmaf(wv, win[kx + j], acc[i][j]);
                }
            }
            if (i >= 1) {
                #pragma unroll
                for (int kx = 0; kx < 13; kx++) {
                    const float wv = ((const float*)w1)[kx];
                    #pragma unroll
                    for (int j = 0; j < 8; j++)
                        acc[i - 1][j] = fmaf(wv, win[kx + j], acc[i - 1][j]);
                }
            }
        }
    }
    // tail ky = 12
    {
        float4 wt[4];
        #pragma unroll
        for (int q = 0; q < 4; q++) wt[q] = ((const float4*)&sw[12 * 16])[q];
        const float* sr = sbase + 12 * PW;
        #pragma unroll
        for (int i = 0; i < 7; i++) {
            float4 win4[5];
            #pragma unroll
            for (int q = 0; q < 5; q++)
                win4[q] = *(const float4*)(sr + i * PW + 4 * q);
            const float* win = (const float*)win4;
            #pragma unroll
            for (int kx = 0; kx < 13; kx++) {
                const float wv = ((const float*)wt)[kx];
                #pragma unroll
                for (int j = 0; j < 8; j++)
                    acc[i][j] = fmaf(wv, win[kx + j], acc[i][j]);
            }
        }
    }

    // --- epilogue: +bias, 2x float4 stores per row, idle col group masked ---
    if (xg < 7) {
        float* op = out + (size_t)plane * (SP * SP) + Yb * SP + 8 * xg;
        #pragma unroll
        for (int r = 0; r < 7; r++) {
            float4 v0 = make_float4(acc[r][0] + bias, acc[r][1] + bias,
                                    acc[r][2] + bias, acc[r][3] + bias);
            float4 v1 = make_float4(acc[r][4] + bias, acc[r][5] + bias,
                                    acc[r][6] + bias, acc[r][7] + bias);
            *(float4*)(op + r * SP) = v0;
            *(float4*)(op + r * SP + 4) = v1;
        }
    }
}

extern "C" void kernel_launch(void* const* d_in, const int* in_sizes, int n_in,
                              void* d_out, int out_size, void* d_ws, size_t ws_size,
                              hipStream_t stream) {
    const float* x    = (const float*)d_in[0];
    const float* w_lk = (const float*)d_in[1];
    const float* w_b0 = (const float*)d_in[2];
    const float* w_b1 = (const float*)d_in[3];
    const float* w_b2 = (const float*)d_in[4];
    const float* w_b3 = (const float*)d_in[5];
    const float* w_b4 = (const float*)d_in[6];
    const float* w_b5 = (const float*)d_in[7];
    const float* bn_g = (const float*)d_in[8];
    const float* bn_b = (const float*)d_in[9];
    const float* bn_m = (const float*)d_in[10];
    const float* bn_v = (const float*)d_in[11];
    float* out = (float*)d_out;

    drb_conv13_w64<<<dim3(NPLANES), dim3(64), 0, stream>>>(
        x, w_lk, w_b0, w_b1, w_b2, w_b3, w_b4, w_b5,
        bn_g, bn_b, bn_m, bn_v, out);
}

// Round 3
// 245.640 us; speedup vs baseline: 1.1488x; 1.0010x over previous
//
#include <hip/hip_runtime.h>

// DilatedReparamBlock folded into one 13x13 depthwise conv + bias.
// Wave-per-plane: block = 64 threads = 1 wave = 1 plane (56x56).
// Thread (xg,yg): 7-row x 8-col output patch (xg<7 active; 8 yg groups).
//
// R3 change: idle lane xg=7 clamps its addresses to xg=3 (was 6).
// Bank base class = (28*yg + 8*xg) mod 32; with clamp->6 the class-16
// banks carried 3 distinct addresses per yg ({xg2,xg6,xg7}) while class-24
// carried 1 -> 12-vs-7 bank imbalance = the 2.2e7 conflict cycles.
// Clamp->3 makes xg7 a same-address broadcast with xg3 (free), balancing
// every bank-quad at 7 distinct addresses per ds_read_b128.

#define CCH 384
#define SP 56
#define PW 68              // 56 + 2*6 padding
#define NPLANES (16*384)

__global__ __launch_bounds__(64) void drb_conv13_w64(
    const float* __restrict__ x,
    const float* __restrict__ w_lk, const float* __restrict__ w_b0,
    const float* __restrict__ w_b1, const float* __restrict__ w_b2,
    const float* __restrict__ w_b3, const float* __restrict__ w_b4,
    const float* __restrict__ w_b5,
    const float* __restrict__ gamma, const float* __restrict__ beta,
    const float* __restrict__ mean, const float* __restrict__ var,
    float* __restrict__ out)
{
    __shared__ __align__(16) float sx[PW * PW];   // 18496 B padded plane
    __shared__ __align__(16) float sw[13 * 16];   // merged weights, rows padded to 16

    const int plane = blockIdx.x;                 // n*384 + c
    const int c = plane % CCH;
    const int tid = threadIdx.x;
    const float* __restrict__ xp = x + (size_t)plane * (SP * SP);

    // --- BN fold constants (wave-uniform -> scalar loads) ---
    float S[7];
    float bias = 0.f;
    #pragma unroll
    for (int j = 0; j < 7; j++) {
        float inv = gamma[j * CCH + c] * rsqrtf(var[j * CCH + c] + 1e-5f);
        S[j] = inv;
        bias += beta[j * CCH + c] - mean[j * CCH + c] * inv;
    }

    // --- zero padded tile (b128 stores); single wave -> no barrier needed ---
    {
        float4 z = make_float4(0.f, 0.f, 0.f, 0.f);
        #pragma unroll
        for (int k = 0; k < 19; k++) {
            int i = tid + 64 * k;
            if (i < PW * PW / 4) ((float4*)sx)[i] = z;
        }
    }

    // --- build merged 13x13 weights (208 slots incl. row pad) ---
    #pragma unroll
    for (int k = 0; k < 4; k++) {
        int t = tid + 64 * k;
        if (t < 13 * 16) {
            int ky = t >> 4, kx = t & 15;
            float w = 0.f;
            if (kx < 13) {
                w = S[0] * w_lk[c * 169 + ky * 13 + kx];                   // 13x13 d1
                if (ky >= 4 && ky <= 8 && kx >= 4 && kx <= 8)              // 5x5 d1 @4
                    w += S[1] * w_b0[c * 25 + (ky - 4) * 5 + (kx - 4)];
                if (ky >= 3 && ky <= 9 && kx >= 3 && kx <= 9)              // 7x7 d1 @3
                    w += S[2] * w_b1[c * 49 + (ky - 3) * 7 + (kx - 3)];
                if (!(ky & 1) && !(kx & 1))                                // 7x7 d2
                    w += S[3] * w_b2[c * 49 + (ky >> 1) * 7 + (kx >> 1)];
                if (ky >= 3 && ky <= 9 && (ky - 3) % 3 == 0 &&
                    kx >= 3 && kx <= 9 && (kx - 3) % 3 == 0)               // 3x3 d3
                    w += S[4] * w_b3[c * 9 + ((ky - 3) / 3) * 3 + (kx - 3) / 3];
                if (ky >= 2 && ky <= 10 && (ky - 2) % 4 == 0 &&
                    kx >= 2 && kx <= 10 && (kx - 2) % 4 == 0)              // 3x3 d4
                    w += S[5] * w_b4[c * 9 + ((ky - 2) / 4) * 3 + (kx - 2) / 4];
                if (ky >= 1 && ky <= 11 && (ky - 1) % 5 == 0 &&
                    kx >= 1 && kx <= 11 && (kx - 1) % 5 == 0)              // 3x3 d5
                    w += S[6] * w_b5[c * 9 + ((ky - 1) / 5) * 3 + (kx - 1) / 5];
            }
            sw[t] = w;
        }
    }

    // --- stage plane: 784 float4 global loads -> 2x b64 LDS writes each ---
    #pragma unroll
    for (int k = 0; k < 13; k++) {
        int i4 = tid + 64 * k;
        if (i4 < SP * SP / 4) {
            float4 v = ((const float4*)xp)[i4];
            int r = i4 / 14;                 // 14 float4 per 56-wide row
            int col = (i4 - r * 14) * 4;
            float* d = &sx[(r + 6) * PW + col + 6];   // word-even -> 8B aligned
            ((float2*)d)[0] = make_float2(v.x, v.y);
            ((float2*)d)[1] = make_float2(v.z, v.w);
        }
    }
    __syncthreads();

    // --- compute: lane (xg,yg) -> out rows [7yg..7yg+6], cols [8xg..8xg+7] ---
    const int xg = tid & 7;
    const int yg = tid >> 3;
    const int xgc = (xg < 7) ? xg : 3;       // idle lane: same-address broadcast with xg=3
    const int Yb = yg * 7;
    const float* __restrict__ sbase = &sx[Yb * PW + 8 * xgc];

    float acc[7][8];
    #pragma unroll
    for (int r = 0; r < 7; r++)
        #pragma unroll
        for (int j = 0; j < 8; j++) acc[r][j] = 0.f;

    // ky pairs (0,1)(2,3)...(10,11): 8 input rows per pair, each serving
    // (r=i, ky=k0) and (r=i-1, ky=k0+1).
    #pragma unroll 1
    for (int k0 = 0; k0 < 12; k0 += 2) {
        float4 w0[4], w1[4];
        #pragma unroll
        for (int q = 0; q < 4; q++) {
            w0[q] = ((const float4*)&sw[k0 * 16])[q];
            w1[q] = ((const float4*)&sw[(k0 + 1) * 16])[q];
        }
        const float* sr = sbase + k0 * PW;
        #pragma unroll
        for (int i = 0; i < 8; i++) {
            float4 win4[5];
            #pragma unroll
            for (int q = 0; q < 5; q++)
                win4[q] = *(const float4*)(sr + i * PW + 4 * q);
            const float* win = (const float*)win4;
            if (i < 7) {
                #pragma unroll
                for (int kx = 0; kx < 13; kx++) {
                    const float wv = ((const float*)w0)[kx];
                    #pragma unroll
                    for (int j = 0; j < 8; j++)
                        acc[i][j] = fmaf(wv, win[kx + j], acc[i][j]);
                }
            }
            if (i >= 1) {
                #pragma unroll
                for (int kx = 0; kx < 13; kx++) {
                    const float wv = ((const float*)w1)[kx];
                    #pragma unroll
                    for (int j = 0; j < 8; j++)
                        acc[i - 1][j] = fmaf(wv, win[kx + j], acc[i - 1][j]);
                }
            }
        }
    }
    // tail ky = 12
    {
        float4 wt[4];
        #pragma unroll
        for (int q = 0; q < 4; q++) wt[q] = ((const float4*)&sw[12 * 16])[q];
        const float* sr = sbase + 12 * PW;
        #pragma unroll
        for (int i = 0; i < 7; i++) {
            float4 win4[5];
            #pragma unroll
            for (int q = 0; q < 5; q++)
                win4[q] = *(const float4*)(sr + i * PW + 4 * q);
            const float* win = (const float*)win4;
            #pragma unroll
            for (int kx = 0; kx < 13; kx++) {
                const float wv = ((const float*)wt)[kx];
                #pragma unroll
                for (int j = 0; j < 8; j++)
                    acc[i][j] = fmaf(wv, win[kx + j], acc[i][j]);
            }
        }
    }

    // --- epilogue: +bias, 2x float4 stores per row, idle col group masked ---
    if (xg < 7) {
        float* op = out + (size_t)plane * (SP * SP) + Yb * SP + 8 * xg;
        #pragma unroll
        for (int r = 0; r < 7; r++) {
            float4 v0 = make_float4(acc[r][0] + bias, acc[r][1] + bias,
                                    acc[r][2] + bias, acc[r][3] + bias);
            float4 v1 = make_float4(acc[r][4] + bias, acc[r][5] + bias,
                                    acc[r][6] + bias, acc[r][7] + bias);
            *(float4*)(op + r * SP) = v0;
            *(float4*)(op + r * SP + 4) = v1;
        }
    }
}

extern "C" void kernel_launch(void* const* d_in, const int* in_sizes, int n_in,
                              void* d_out, int out_size, void* d_ws, size_t ws_size,
                              hipStream_t stream) {
    const float* x    = (const float*)d_in[0];
    const float* w_lk = (const float*)d_in[1];
    const float* w_b0 = (const float*)d_in[2];
    const float* w_b1 = (const float*)d_in[3];
    const float* w_b2 = (const float*)d_in[4];
    const float* w_b3 = (const float*)d_in[5];
    const float* w_b4 = (const float*)d_in[6];
    const float* w_b5 = (const float*)d_in[7];
    const float* bn_g = (const float*)d_in[8];
    const float* bn_b = (const float*)d_in[9];
    const float* bn_m = (const float*)d_in[10];
    const float* bn_v = (const float*)d_in[11];
    float* out = (float*)d_out;

    drb_conv13_w64<<<dim3(NPLANES), dim3(64), 0, stream>>>(
        x, w_lk, w_b0, w_b1, w_b2, w_b3, w_b4, w_b5,
        bn_g, bn_b, bn_m, bn_v, out);
}